// Round 6
// baseline (50.802 us; speedup 1.0000x reference)
//
#include <hip/hip_runtime.h>
#include <hip/hip_bf16.h>

#define NB 8
#define NT 2048
#define ND 1024
#define NS 512
#define NW 16

typedef float f32x4 __attribute__((ext_vector_type(4)));

// One block per (b, s) span; 4 waves of 64.
// Wave v owns rows 4v..4v+3. Lane l holds each row's 4 float4 chunks at
// float cols 4l + 256k (k=0..3) -> whole row covered by the wave, each
// global load is one coalesced 1KB burst.
// Phase 1: gather rows ONCE, dot vs att_w on the fly, pack rows to bf16
//          pairs in REGISTERS (32 VGPR), butterfly-reduce 4 logits,
//          lane 0 writes masked logits to LDS.
// Phase 2: after one barrier, softmax denominator from the 16 LDS logits
//          (per-wave weights only for own 4 rows -> no 16-wide reg arrays),
//          pool own rows from registers, write per-wave partials to LDS,
//          barrier, 4-way add, store.
// LDS 16.3 KB + VGPR<=85 -> 6 waves/SIMD (24 waves/CU), vs 16 waves before.
__global__ __launch_bounds__(256, 6) void span_attn_kernel(
    const float* __restrict__ text,   // [B, T, D]
    const int*   __restrict__ wi,     // [B, S, W]
    const int*   __restrict__ wm,     // [B, S, W]
    const int*   __restrict__ wim,    // [B, S]
    const float* __restrict__ att_w,  // [D]
    const float* __restrict__ att_b,  // [1]
    float*       __restrict__ out)    // [B, S, D]
{
    const int b    = blockIdx.x & (NB - 1);   // XCD-aligned batch
    const int s    = blockIdx.x >> 3;
    const int bs   = b * NS + s;
    const int tid  = threadIdx.x;
    const int lane = tid & 63;
    const int wv   = tid >> 6;

    __shared__ float red[NW];          // masked logits
    __shared__ float part[4][ND];      // per-wave pool partials, 16 KB

    const int* wip = wi + (size_t)bs * NW;
    const int* wmp = wm + (size_t)bs * NW;
    const float* tbase = text + (size_t)b * NT * ND + 4 * lane;

    // att_w fragments for this lane's chunk columns.
    f32x4 wfrag[4];
    #pragma unroll
    for (int k = 0; k < 4; ++k)
        wfrag[k] = *reinterpret_cast<const f32x4*>(att_w + 4 * lane + 256 * k);
    const float bias = att_b[0];

    int   idx[4];
    float mk[4];
    #pragma unroll
    for (int r = 0; r < 4; ++r) {
        int v  = wip[4 * wv + r];
        idx[r] = v > 0 ? v : 0;               // relu clamp
        mk[r]  = (float)wmp[4 * wv + r];
    }

    // ---- Phase 1: single gather; dot + bf16 pack to registers ----
    unsigned int rowbf[4][4][2];   // [row][chunk][pair] = 32 VGPRs
    float p[4];
    #pragma unroll
    for (int r = 0; r < 4; ++r) {
        const float* src = tbase + (size_t)idx[r] * ND;
        float acc = 0.0f;
        #pragma unroll
        for (int k = 0; k < 4; ++k) {
            const f32x4 f = *reinterpret_cast<const f32x4*>(src + 256 * k);
            acc += f.x * wfrag[k].x + f.y * wfrag[k].y
                 + f.z * wfrag[k].z + f.w * wfrag[k].w;
            __hip_bfloat162 h0 = __float22bfloat162_rn(make_float2(f.x, f.y));
            __hip_bfloat162 h1 = __float22bfloat162_rn(make_float2(f.z, f.w));
            unsigned int u0, u1;
            __builtin_memcpy(&u0, &h0, 4);
            __builtin_memcpy(&u1, &h1, 4);
            rowbf[r][k][0] = u0;
            rowbf[r][k][1] = u1;
        }
        p[r] = acc;
    }

    // Butterfly-reduce the 4 dot partials across the wave.
    #pragma unroll
    for (int r = 0; r < 4; ++r) {
        float v = p[r];
        v += __shfl_xor(v, 1);
        v += __shfl_xor(v, 2);
        v += __shfl_xor(v, 4);
        v += __shfl_xor(v, 8);
        v += __shfl_xor(v, 16);
        v += __shfl_xor(v, 32);
        p[r] = v;
    }
    if (lane == 0) {
        #pragma unroll
        for (int r = 0; r < 4; ++r)
            red[4 * wv + r] = (mk[r] != 0.0f) ? (p[r] + bias) : -1.0e9f;
    }
    __syncthreads();

    // ---- Softmax denominator from LDS logits (scalar regs only) ----
    float m = -3.0e38f;
    #pragma unroll
    for (int i = 0; i < NW; ++i) m = fmaxf(m, red[i]);
    float sum = 0.0f;
    #pragma unroll
    for (int i = 0; i < NW; ++i) sum += __expf(red[i] - m);
    const float inv = 1.0f / sum;

    float wgt[4];
    #pragma unroll
    for (int r = 0; r < 4; ++r)
        wgt[r] = __expf(red[4 * wv + r] - m) * inv * mk[r];

    // ---- Pool own rows from registers ----
    f32x4 acc[4];
    #pragma unroll
    for (int k = 0; k < 4; ++k) acc[k] = (f32x4){0.f, 0.f, 0.f, 0.f};
    #pragma unroll
    for (int r = 0; r < 4; ++r) {
        #pragma unroll
        for (int k = 0; k < 4; ++k) {
            const unsigned int u0 = rowbf[r][k][0];
            const unsigned int u1 = rowbf[r][k][1];
            acc[k].x += wgt[r] * __uint_as_float(u0 << 16);
            acc[k].y += wgt[r] * __uint_as_float(u0 & 0xFFFF0000u);
            acc[k].z += wgt[r] * __uint_as_float(u1 << 16);
            acc[k].w += wgt[r] * __uint_as_float(u1 & 0xFFFF0000u);
        }
    }
    #pragma unroll
    for (int k = 0; k < 4; ++k)
        *reinterpret_cast<f32x4*>(&part[wv][4 * lane + 256 * k]) = acc[k];
    __syncthreads();

    // ---- Final 4-way add; thread t owns output cols 4t..4t+3 ----
    f32x4 o = *reinterpret_cast<const f32x4*>(&part[0][4 * tid]);
    #pragma unroll
    for (int v = 1; v < 4; ++v) {
        const f32x4 q = *reinterpret_cast<const f32x4*>(&part[v][4 * tid]);
        o.x += q.x; o.y += q.y; o.z += q.z; o.w += q.w;
    }
    const float sm = (float)wim[bs];
    o.x *= sm; o.y *= sm; o.z *= sm; o.w *= sm;
    __builtin_nontemporal_store(o,
        reinterpret_cast<f32x4*>(out + (size_t)bs * ND + 4 * tid));
}

extern "C" void kernel_launch(void* const* d_in, const int* in_sizes, int n_in,
                              void* d_out, int out_size, void* d_ws, size_t ws_size,
                              hipStream_t stream) {
    const float* text  = (const float*)d_in[0];
    // d_in[1] = contextualized_embedding: unused by the reference.
    const int*   wi    = (const int*)d_in[2];
    const int*   wm    = (const int*)d_in[3];
    const int*   wim   = (const int*)d_in[4];
    const float* att_w = (const float*)d_in[5];
    const float* att_b = (const float*)d_in[6];
    float*       out   = (float*)d_out;

    dim3 grid(NB * NS);
    dim3 block(256);
    span_attn_kernel<<<grid, block, 0, stream>>>(text, wi, wm, wim, att_w, att_b, out);
}

// Round 7
// 30.468 us; speedup vs baseline: 1.6674x; 1.6674x over previous
//
#include <hip/hip_runtime.h>

#define NB 8
#define NT 2048
#define ND 1024
#define NS 512
#define NW 16

typedef float f32x4 __attribute__((ext_vector_type(4)));

// ---------------- Pass 1: global logits ----------------
// logits[b*T+t] = dot(text[b,t,:], att_w) + bias.  Pure stream of text
// (64 MB) at HBM BW. One wave per row; lane l covers float cols 4l+256k.
__global__ __launch_bounds__(256) void logit_kernel(
    const float* __restrict__ text,   // [B, T, D]
    const float* __restrict__ att_w,  // [D]
    const float* __restrict__ att_b,  // [1]
    float*       __restrict__ logits) // [B*T]
{
    const int row  = blockIdx.x * 4 + (threadIdx.x >> 6);  // b*T + t
    const int lane = threadIdx.x & 63;

    const float* src = text + (size_t)row * ND + 4 * lane;
    const float* wp  = att_w + 4 * lane;

    float acc = 0.0f;
    #pragma unroll
    for (int k = 0; k < 4; ++k) {
        const f32x4 f = *reinterpret_cast<const f32x4*>(src + 256 * k);
        const f32x4 w = *reinterpret_cast<const f32x4*>(wp + 256 * k);
        acc += f.x * w.x + f.y * w.y + f.z * w.z + f.w * w.w;
    }
    acc += __shfl_xor(acc, 1);
    acc += __shfl_xor(acc, 2);
    acc += __shfl_xor(acc, 4);
    acc += __shfl_xor(acc, 8);
    acc += __shfl_xor(acc, 16);
    acc += __shfl_xor(acc, 32);
    if (lane == 0) logits[row] = acc + att_b[0];
}

// ---------------- Pass 2: span pooling ----------------
// Weights are known BEFORE the gather -> single pass, no LDS, no barrier.
// Skips: wim==0 span -> write zeros, no gather (~50% of spans);
//        word_mask==0 row -> weight is exactly 0 -> skip the row load.
// XCD swizzle: b = blockIdx & 7 keeps each XCD's gathers inside text[b].
__global__ __launch_bounds__(256) void pool_kernel(
    const float* __restrict__ text,   // [B, T, D]
    const float* __restrict__ logits, // [B*T]
    const int*   __restrict__ wi,     // [B, S, W]
    const int*   __restrict__ wm,     // [B, S, W]
    const int*   __restrict__ wim,    // [B, S]
    float*       __restrict__ out)    // [B, S, D]
{
    const int b   = blockIdx.x & (NB - 1);
    const int s   = blockIdx.x >> 3;
    const int bs  = b * NS + s;
    const int tid = threadIdx.x;

    f32x4* op = reinterpret_cast<f32x4*>(out + (size_t)bs * ND + 4 * tid);

    if (wim[bs] == 0) {               // uniform branch: whole span is zero
        __builtin_nontemporal_store((f32x4){0.f, 0.f, 0.f, 0.f}, op);
        return;
    }

    const int* wip = wi + (size_t)bs * NW;
    const int* wmp = wm + (size_t)bs * NW;
    const float* lg = logits + (size_t)b * NT;

    int idx[NW];
    float ml[NW];
    unsigned mkbits = 0;
    #pragma unroll
    for (int w = 0; w < NW; ++w) {
        const int v = wip[w];
        idx[w] = v > 0 ? v : 0;       // relu clamp, matches reference
        const int mkv = wmp[w];
        mkbits |= (mkv != 0) ? (1u << w) : 0u;
        ml[w] = (mkv != 0) ? lg[idx[w]] : -1.0e9f;
    }

    // Redundant per-thread 16-wide softmax (cheap, all in registers).
    float m = -3.0e38f;
    #pragma unroll
    for (int w = 0; w < NW; ++w) m = fmaxf(m, ml[w]);
    float e[NW];
    float sum = 0.0f;
    #pragma unroll
    for (int w = 0; w < NW; ++w) {
        e[w] = __expf(ml[w] - m);
        sum += e[w];
    }
    const float inv = 1.0f / sum;

    // Gather + weighted sum; masked rows never loaded.
    const float* tb = text + (size_t)b * NT * ND + 4 * tid;
    f32x4 acc = (f32x4){0.f, 0.f, 0.f, 0.f};
    #pragma unroll
    for (int w = 0; w < NW; ++w) {
        if (mkbits & (1u << w)) {     // uniform per block
            const f32x4 f = *reinterpret_cast<const f32x4*>(tb + (size_t)idx[w] * ND);
            const float wgt = e[w] * inv;
            acc.x += wgt * f.x;
            acc.y += wgt * f.y;
            acc.z += wgt * f.z;
            acc.w += wgt * f.w;
        }
    }
    __builtin_nontemporal_store(acc, op);
}

extern "C" void kernel_launch(void* const* d_in, const int* in_sizes, int n_in,
                              void* d_out, int out_size, void* d_ws, size_t ws_size,
                              hipStream_t stream) {
    const float* text  = (const float*)d_in[0];
    // d_in[1] = contextualized_embedding: unused by the reference.
    const int*   wi    = (const int*)d_in[2];
    const int*   wm    = (const int*)d_in[3];
    const int*   wim   = (const int*)d_in[4];
    const float* att_w = (const float*)d_in[5];
    const float* att_b = (const float*)d_in[6];
    float*       out   = (float*)d_out;
    float*       logits = (float*)d_ws;     // needs B*T*4 = 64 KB of scratch

    logit_kernel<<<dim3(NB * NT / 4), dim3(256), 0, stream>>>(text, att_w, att_b, logits);
    pool_kernel<<<dim3(NB * NS), dim3(256), 0, stream>>>(text, logits, wi, wm, wim, out);
}

// Round 8
// 28.980 us; speedup vs baseline: 1.7530x; 1.0514x over previous
//
#include <hip/hip_runtime.h>

#define NB 8
#define NT 2048
#define ND 1024
#define NS 512
#define NW 16

typedef float f32x4 __attribute__((ext_vector_type(4)));

// ---------------- Pass 1: global logits ----------------
// 2 rows per wave: lane l covers float cols 4l+256k of both rows -> 8
// independent 16B loads in flight per thread. Grid 2048 blocks.
__global__ __launch_bounds__(256) void logit_kernel(
    const float* __restrict__ text,   // [B, T, D]
    const float* __restrict__ att_w,  // [D]
    const float* __restrict__ att_b,  // [1]
    float*       __restrict__ logits) // [B*T]
{
    const int row0 = blockIdx.x * 8 + (threadIdx.x >> 6) * 2;  // b*T + t
    const int lane = threadIdx.x & 63;

    const float* src0 = text + (size_t)row0 * ND + 4 * lane;
    const float* src1 = src0 + ND;
    const float* wp   = att_w + 4 * lane;

    f32x4 w[4], f0[4], f1[4];
    #pragma unroll
    for (int k = 0; k < 4; ++k) {
        f0[k] = *reinterpret_cast<const f32x4*>(src0 + 256 * k);
        f1[k] = *reinterpret_cast<const f32x4*>(src1 + 256 * k);
        w[k]  = *reinterpret_cast<const f32x4*>(wp + 256 * k);
    }
    float a0 = 0.0f, a1 = 0.0f;
    #pragma unroll
    for (int k = 0; k < 4; ++k) {
        a0 += f0[k].x * w[k].x + f0[k].y * w[k].y + f0[k].z * w[k].z + f0[k].w * w[k].w;
        a1 += f1[k].x * w[k].x + f1[k].y * w[k].y + f1[k].z * w[k].z + f1[k].w * w[k].w;
    }
    #pragma unroll
    for (int d = 1; d < 64; d <<= 1) {
        a0 += __shfl_xor(a0, d);
        a1 += __shfl_xor(a1, d);
    }
    if (lane == 0) {
        const float bias = att_b[0];
        logits[row0]     = a0 + bias;
        logits[row0 + 1] = a1 + bias;
    }
}

// ---------------- Pass 2: span pooling ----------------
// 2 spans per block; all metadata VMEM issued up front; weights known
// before the gather -> single gather pass, no LDS, no barrier.
// XCD swizzle: b = blockIdx & 7 keeps each XCD's gathers inside text[b].
__global__ __launch_bounds__(256) void pool_kernel(
    const float* __restrict__ text,   // [B, T, D]
    const float* __restrict__ logits, // [B*T]
    const int*   __restrict__ wi,     // [B, S, W]
    const int*   __restrict__ wm,     // [B, S, W]
    const int*   __restrict__ wim,    // [B, S]
    float*       __restrict__ out)    // [B, S, D]
{
    const int b   = blockIdx.x & (NB - 1);
    const int s0  = (blockIdx.x >> 3) * 2;
    const int tid = threadIdx.x;

    const float* lg = logits + (size_t)b * NT;
    const float* tb = text + (size_t)b * NT * ND + 4 * tid;

    #pragma unroll
    for (int sp = 0; sp < 2; ++sp) {
        const int s  = s0 + sp;
        const int bs = b * NS + s;
        f32x4* op = reinterpret_cast<f32x4*>(out + (size_t)bs * ND + 4 * tid);

        const int span_on = wim[bs];

        // Vectorized metadata loads: 4 + 4 int4s.
        const int* wip = wi + (size_t)bs * NW;
        const int* wmp = wm + (size_t)bs * NW;
        int4 iv[4], mv[4];
        #pragma unroll
        for (int q = 0; q < 4; ++q) {
            iv[q] = *reinterpret_cast<const int4*>(wip + 4 * q);
            mv[q] = *reinterpret_cast<const int4*>(wmp + 4 * q);
        }

        if (span_on == 0) {           // uniform: whole span is exactly zero
            __builtin_nontemporal_store((f32x4){0.f, 0.f, 0.f, 0.f}, op);
            continue;
        }

        int idx[NW];
        unsigned mkbits = 0;
        #pragma unroll
        for (int q = 0; q < 4; ++q) {
            const int* ip = &iv[q].x;
            const int* mp = &mv[q].x;
            #pragma unroll
            for (int j = 0; j < 4; ++j) {
                const int w = 4 * q + j;
                const int v = ip[j];
                idx[w] = v > 0 ? v : 0;       // relu clamp
                mkbits |= (mp[j] != 0) ? (1u << w) : 0u;
            }
        }

        float ml[NW];
        #pragma unroll
        for (int w = 0; w < NW; ++w)
            ml[w] = (mkbits & (1u << w)) ? lg[idx[w]] : -1.0e9f;

        float m = -3.0e38f;
        #pragma unroll
        for (int w = 0; w < NW; ++w) m = fmaxf(m, ml[w]);
        float e[NW];
        float sum = 0.0f;
        #pragma unroll
        for (int w = 0; w < NW; ++w) {
            e[w] = __expf(ml[w] - m);
            sum += e[w];
        }
        const float inv = 1.0f / sum;

        // Gather + weighted sum; masked rows never loaded.
        f32x4 acc = (f32x4){0.f, 0.f, 0.f, 0.f};
        #pragma unroll
        for (int w = 0; w < NW; ++w) {
            if (mkbits & (1u << w)) {         // uniform per block
                const f32x4 f = *reinterpret_cast<const f32x4*>(tb + (size_t)idx[w] * ND);
                const float wgt = e[w] * inv;
                acc.x += wgt * f.x;
                acc.y += wgt * f.y;
                acc.z += wgt * f.z;
                acc.w += wgt * f.w;
            }
        }
        __builtin_nontemporal_store(acc, op);
    }
}

extern "C" void kernel_launch(void* const* d_in, const int* in_sizes, int n_in,
                              void* d_out, int out_size, void* d_ws, size_t ws_size,
                              hipStream_t stream) {
    const float* text  = (const float*)d_in[0];
    // d_in[1] = contextualized_embedding: unused by the reference.
    const int*   wi    = (const int*)d_in[2];
    const int*   wm    = (const int*)d_in[3];
    const int*   wim   = (const int*)d_in[4];
    const float* att_w = (const float*)d_in[5];
    const float* att_b = (const float*)d_in[6];
    float*       out   = (float*)d_out;
    float*       logits = (float*)d_ws;     // needs B*T*4 = 64 KB of scratch

    logit_kernel<<<dim3(NB * NT / 8), dim3(256), 0, stream>>>(text, att_w, att_b, logits);
    pool_kernel<<<dim3(NB * NS / 2), dim3(256), 0, stream>>>(text, logits, wi, wm, wim, out);
}

// Round 9
// 18.629 us; speedup vs baseline: 2.7270x; 1.5556x over previous
//
#include <hip/hip_runtime.h>
#include <hip/hip_bf16.h>

#define NB 8
#define NT 2048
#define ND 1024
#define NS 512
#define NW 16

typedef float f32x4 __attribute__((ext_vector_type(4)));

// One block per (b, s) span; 4 waves. Wave wv owns rows 4wv..4wv+3; lane l
// covers float cols 4l + 256k (k=0..3) of each row.
// Skips (both wave-uniform):
//   wim[bs]==0  -> whole span is exactly 0: store zeros, exit, no gather.
//   wm[w]==0    -> row weight is exactly 0: row never loaded.
// Phase 1: gather own unmasked rows ONCE; dot vs att_w on the fly; pack rows
//          to bf16 pairs in REGISTERS (32 VGPR); butterfly logits; LDS red[16].
// Phase 2: softmax from red[16]; pool own rows from registers; per-wave
//          partials to LDS; 4-way add; store.
// NO forced launch bounds: round-6's (256,6) squeezed VGPR to 40 -> scratch
// spill (WRITE_SIZE 68 MB). Compiler should settle ~110 VGPR, no spill.
__global__ __launch_bounds__(256) void span_attn_kernel(
    const float* __restrict__ text,   // [B, T, D]
    const int*   __restrict__ wi,     // [B, S, W]
    const int*   __restrict__ wm,     // [B, S, W]
    const int*   __restrict__ wim,    // [B, S]
    const float* __restrict__ att_w,  // [D]
    const float* __restrict__ att_b,  // [1]
    float*       __restrict__ out)    // [B, S, D]
{
    const int b    = blockIdx.x & (NB - 1);   // XCD-aligned batch
    const int s    = blockIdx.x >> 3;
    const int bs   = b * NS + s;
    const int tid  = threadIdx.x;
    const int lane = tid & 63;
    const int wv   = tid >> 6;

    f32x4* op = reinterpret_cast<f32x4*>(out + (size_t)bs * ND + 4 * tid);

    if (wim[bs] == 0) {                // uniform across block: exit together
        __builtin_nontemporal_store((f32x4){0.f, 0.f, 0.f, 0.f}, op);
        return;
    }

    __shared__ float red[NW];          // masked logits
    __shared__ float part[4][ND];      // per-wave pool partials, 16 KB

    const int* wip = wi + (size_t)bs * NW;
    const int* wmp = wm + (size_t)bs * NW;

    int   idx[4];
    float mk[4];
    #pragma unroll
    for (int r = 0; r < 4; ++r) {
        const int v = wip[4 * wv + r];
        idx[r] = v > 0 ? v : 0;        // relu clamp
        mk[r]  = (float)wmp[4 * wv + r];
    }

    // att_w fragments for this lane's chunk columns (L1-resident).
    f32x4 wfrag[4];
    #pragma unroll
    for (int k = 0; k < 4; ++k)
        wfrag[k] = *reinterpret_cast<const f32x4*>(att_w + 4 * lane + 256 * k);
    const float bias = att_b[0];

    const float* tbase = text + (size_t)b * NT * ND + 4 * lane;

    // ---- Phase 1: gather own unmasked rows once; dot + bf16 pack ----
    unsigned int rowbf[4][4][2];       // [row][chunk][pair] = 32 VGPRs
    float p[4];
    #pragma unroll
    for (int r = 0; r < 4; ++r) {
        p[r] = 0.0f;
        if (mk[r] != 0.0f) {           // wave-uniform: skip masked rows
            const float* src = tbase + (size_t)idx[r] * ND;
            float acc = 0.0f;
            #pragma unroll
            for (int k = 0; k < 4; ++k) {
                const f32x4 f = *reinterpret_cast<const f32x4*>(src + 256 * k);
                acc += f.x * wfrag[k].x + f.y * wfrag[k].y
                     + f.z * wfrag[k].z + f.w * wfrag[k].w;
                __hip_bfloat162 h0 = __float22bfloat162_rn(make_float2(f.x, f.y));
                __hip_bfloat162 h1 = __float22bfloat162_rn(make_float2(f.z, f.w));
                unsigned int u0, u1;
                __builtin_memcpy(&u0, &h0, 4);
                __builtin_memcpy(&u1, &h1, 4);
                rowbf[r][k][0] = u0;
                rowbf[r][k][1] = u1;
            }
            p[r] = acc;
        }
    }

    // Butterfly-reduce the 4 dot partials across the wave.
    #pragma unroll
    for (int r = 0; r < 4; ++r) {
        float v = p[r];
        v += __shfl_xor(v, 1);
        v += __shfl_xor(v, 2);
        v += __shfl_xor(v, 4);
        v += __shfl_xor(v, 8);
        v += __shfl_xor(v, 16);
        v += __shfl_xor(v, 32);
        p[r] = v;
    }
    if (lane == 0) {
        #pragma unroll
        for (int r = 0; r < 4; ++r)
            red[4 * wv + r] = (mk[r] != 0.0f) ? (p[r] + bias) : -1.0e9f;
    }
    __syncthreads();

    // ---- Softmax over the 16 LDS logits (scalar regs only) ----
    float m = -3.0e38f;
    #pragma unroll
    for (int i = 0; i < NW; ++i) m = fmaxf(m, red[i]);
    float sum = 0.0f;
    #pragma unroll
    for (int i = 0; i < NW; ++i) sum += __expf(red[i] - m);
    const float inv = 1.0f / sum;

    float wgt[4];
    #pragma unroll
    for (int r = 0; r < 4; ++r)
        wgt[r] = (mk[r] != 0.0f) ? __expf(red[4 * wv + r] - m) * inv : 0.0f;

    // ---- Phase 2: pool own rows from registers ----
    f32x4 acc[4];
    #pragma unroll
    for (int k = 0; k < 4; ++k) acc[k] = (f32x4){0.f, 0.f, 0.f, 0.f};
    #pragma unroll
    for (int r = 0; r < 4; ++r) {
        if (mk[r] != 0.0f) {           // wave-uniform
            #pragma unroll
            for (int k = 0; k < 4; ++k) {
                const unsigned int u0 = rowbf[r][k][0];
                const unsigned int u1 = rowbf[r][k][1];
                acc[k].x += wgt[r] * __uint_as_float(u0 << 16);
                acc[k].y += wgt[r] * __uint_as_float(u0 & 0xFFFF0000u);
                acc[k].z += wgt[r] * __uint_as_float(u1 << 16);
                acc[k].w += wgt[r] * __uint_as_float(u1 & 0xFFFF0000u);
            }
        }
    }
    #pragma unroll
    for (int k = 0; k < 4; ++k)
        *reinterpret_cast<f32x4*>(&part[wv][4 * lane + 256 * k]) = acc[k];
    __syncthreads();

    // ---- Final 4-way add; thread t owns output cols 4t..4t+3 ----
    f32x4 o = *reinterpret_cast<const f32x4*>(&part[0][4 * tid]);
    #pragma unroll
    for (int v = 1; v < 4; ++v) {
        const f32x4 q = *reinterpret_cast<const f32x4*>(&part[v][4 * tid]);
        o.x += q.x; o.y += q.y; o.z += q.z; o.w += q.w;
    }
    __builtin_nontemporal_store(o, op);
}

extern "C" void kernel_launch(void* const* d_in, const int* in_sizes, int n_in,
                              void* d_out, int out_size, void* d_ws, size_t ws_size,
                              hipStream_t stream) {
    const float* text  = (const float*)d_in[0];
    // d_in[1] = contextualized_embedding: unused by the reference.
    const int*   wi    = (const int*)d_in[2];
    const int*   wm    = (const int*)d_in[3];
    const int*   wim   = (const int*)d_in[4];
    const float* att_w = (const float*)d_in[5];
    const float* att_b = (const float*)d_in[6];
    float*       out   = (float*)d_out;

    span_attn_kernel<<<dim3(NB * NS), dim3(256), 0, stream>>>(
        text, wi, wm, wim, att_w, att_b, out);
}

// Round 10
// 16.342 us; speedup vs baseline: 3.1086x; 1.1399x over previous
//
#include <hip/hip_runtime.h>

#define NB 8
#define NT 2048
#define ND 1024
#define NS 512
#define NW 16

typedef float f32x4 __attribute__((ext_vector_type(4)));

// Wave-per-span: block = 4 waves = 4 consecutive spans of ONE batch.
// Lane l covers float cols 4l + 256k (k=0..3): every load/store instruction
// is a contiguous 1KB burst across the wave.
// Per unmasked row: gather 4 chunks -> dot vs att_w -> butterfly -> e=exp(logit)
// -> acc += e*chunks (row retired from registers immediately). Normalize by
// 1/sum(e) at the end. Unnormalized exp == softmax exactly (ratio); esum==0
// guard reproduces the reference's all-masked-span -> 0 (weights*mask==0).
// No LDS, no barriers, no bf16 round-trip. Grid = 1024 blocks -> fully
// resident (4 blocks/CU); zero-spans exit per-wave without blocking others.
// XCD swizzle: b = blockIdx & 7 keeps each XCD's gathers inside text[b] (8MB).
__global__ __launch_bounds__(256) void span_attn_kernel(
    const float* __restrict__ text,   // [B, T, D]
    const int*   __restrict__ wi,     // [B, S, W]
    const int*   __restrict__ wm,     // [B, S, W]
    const int*   __restrict__ wim,    // [B, S]
    const float* __restrict__ att_w,  // [D]
    const float* __restrict__ att_b,  // [1]
    float*       __restrict__ out)    // [B, S, D]
{
    const int b    = blockIdx.x & (NB - 1);
    const int wv   = threadIdx.x >> 6;
    const int lane = threadIdx.x & 63;
    const int s    = (blockIdx.x >> 3) * 4 + wv;
    const int bs   = b * NS + s;

    float* orow = out + (size_t)bs * ND + 4 * lane;

    if (wim[bs] == 0) {                    // wave-uniform: span is exactly 0
        #pragma unroll
        for (int k = 0; k < 4; ++k)
            __builtin_nontemporal_store((f32x4){0.f, 0.f, 0.f, 0.f},
                reinterpret_cast<f32x4*>(orow + 256 * k));
        return;
    }

    // Span metadata (vector loads, wave-uniform values).
    const int* wip = wi + (size_t)bs * NW;
    const int* wmp = wm + (size_t)bs * NW;
    int iarr[NW], marr[NW];
    #pragma unroll
    for (int q = 0; q < 4; ++q) {
        const int4 iv = *reinterpret_cast<const int4*>(wip + 4 * q);
        const int4 mv = *reinterpret_cast<const int4*>(wmp + 4 * q);
        iarr[4 * q + 0] = iv.x; iarr[4 * q + 1] = iv.y;
        iarr[4 * q + 2] = iv.z; iarr[4 * q + 3] = iv.w;
        marr[4 * q + 0] = mv.x; marr[4 * q + 1] = mv.y;
        marr[4 * q + 2] = mv.z; marr[4 * q + 3] = mv.w;
    }

    f32x4 wfrag[4];
    #pragma unroll
    for (int k = 0; k < 4; ++k)
        wfrag[k] = *reinterpret_cast<const f32x4*>(att_w + 4 * lane + 256 * k);
    const float bias = att_b[0];

    const float* tbase = text + (size_t)b * NT * ND + 4 * lane;

    f32x4 acc[4];
    #pragma unroll
    for (int k = 0; k < 4; ++k) acc[k] = (f32x4){0.f, 0.f, 0.f, 0.f};
    float esum = 0.0f;

    #pragma unroll
    for (int r = 0; r < NW; ++r) {
        if (marr[r] != 0) {                // wave-uniform skip: weight == 0
            const int t = iarr[r] > 0 ? iarr[r] : 0;   // relu clamp
            const float* src = tbase + (size_t)t * ND;
            f32x4 f[4];
            #pragma unroll
            for (int k = 0; k < 4; ++k)
                f[k] = *reinterpret_cast<const f32x4*>(src + 256 * k);

            float d = 0.0f;
            #pragma unroll
            for (int k = 0; k < 4; ++k)
                d += f[k].x * wfrag[k].x + f[k].y * wfrag[k].y
                   + f[k].z * wfrag[k].z + f[k].w * wfrag[k].w;
            d += __shfl_xor(d, 1);
            d += __shfl_xor(d, 2);
            d += __shfl_xor(d, 4);
            d += __shfl_xor(d, 8);
            d += __shfl_xor(d, 16);
            d += __shfl_xor(d, 32);

            const float e = __expf(d + bias);
            esum += e;
            #pragma unroll
            for (int k = 0; k < 4; ++k) {
                acc[k].x += e * f[k].x;
                acc[k].y += e * f[k].y;
                acc[k].z += e * f[k].z;
                acc[k].w += e * f[k].w;
            }
        }
    }

    const float inv = esum > 0.0f ? 1.0f / esum : 0.0f;
    #pragma unroll
    for (int k = 0; k < 4; ++k) {
        f32x4 o = acc[k];
        o.x *= inv; o.y *= inv; o.z *= inv; o.w *= inv;
        __builtin_nontemporal_store(o, reinterpret_cast<f32x4*>(orow + 256 * k));
    }
}

extern "C" void kernel_launch(void* const* d_in, const int* in_sizes, int n_in,
                              void* d_out, int out_size, void* d_ws, size_t ws_size,
                              hipStream_t stream) {
    const float* text  = (const float*)d_in[0];
    // d_in[1] = contextualized_embedding: unused by the reference.
    const int*   wi    = (const int*)d_in[2];
    const int*   wm    = (const int*)d_in[3];
    const int*   wim   = (const int*)d_in[4];
    const float* att_w = (const float*)d_in[5];
    const float* att_b = (const float*)d_in[6];
    float*       out   = (float*)d_out;

    span_attn_kernel<<<dim3(NB * NS / 4), dim3(256), 0, stream>>>(
        text, wi, wm, wim, att_w, att_b, out);
}

// Round 11
// 15.625 us; speedup vs baseline: 3.2513x; 1.0459x over previous
//
#include <hip/hip_runtime.h>

#define NB 8
#define NT 2048
#define ND 1024
#define NS 512
#define NW 16

typedef float f32x4 __attribute__((ext_vector_type(4)));

// One WAVE (64-thread block) per span; grid 4096 blocks -> hardware refills
// CU slots as blocks finish => dynamic load balancing (round-10's fixed
// 4-block/CU residency made the kernel wait on the unluckiest CU, ~1.6x tail).
// Lane l covers float cols 4l + 256k (k=0..3): 1KB contiguous bursts.
// Unmasked rows are pulled from a bitmask and processed in PAIRS: 8 loads
// in flight + two interleaved butterfly chains (vs 4 loads + serial chain
// when each row hides behind its own branch).
// Unnormalized-exp softmax: e=exp(logit+bias) accumulated raw, normalized by
// 1/sum at the end; esum==0 -> zeros matches reference all-masked semantics.
// XCD swizzle: b = blockIdx & 7 keeps each XCD's gathers inside text[b] (8MB).
__global__ __launch_bounds__(64) void span_attn_kernel(
    const float* __restrict__ text,   // [B, T, D]
    const int*   __restrict__ wi,     // [B, S, W]
    const int*   __restrict__ wm,     // [B, S, W]
    const int*   __restrict__ wim,    // [B, S]
    const float* __restrict__ att_w,  // [D]
    const float* __restrict__ att_b,  // [1]
    float*       __restrict__ out)    // [B, S, D]
{
    const int b    = blockIdx.x & (NB - 1);
    const int s    = blockIdx.x >> 3;
    const int bs   = b * NS + s;
    const int lane = threadIdx.x;

    float* orow = out + (size_t)bs * ND + 4 * lane;

    if (wim[bs] == 0) {                    // uniform: span is exactly 0
        #pragma unroll
        for (int k = 0; k < 4; ++k)
            __builtin_nontemporal_store((f32x4){0.f, 0.f, 0.f, 0.f},
                reinterpret_cast<f32x4*>(orow + 256 * k));
        return;
    }

    const int* wip = wi + (size_t)bs * NW;
    const int* wmp = wm + (size_t)bs * NW;

    // Bitmask of unmasked rows (wave-uniform value in every lane).
    unsigned mkbits = 0;
    #pragma unroll
    for (int q = 0; q < 4; ++q) {
        const int4 mv = *reinterpret_cast<const int4*>(wmp + 4 * q);
        mkbits |= (mv.x != 0 ? 1u : 0u) << (4 * q + 0);
        mkbits |= (mv.y != 0 ? 1u : 0u) << (4 * q + 1);
        mkbits |= (mv.z != 0 ? 1u : 0u) << (4 * q + 2);
        mkbits |= (mv.w != 0 ? 1u : 0u) << (4 * q + 3);
    }

    f32x4 wfrag[4];
    #pragma unroll
    for (int k = 0; k < 4; ++k)
        wfrag[k] = *reinterpret_cast<const f32x4*>(att_w + 4 * lane + 256 * k);
    const float bias = att_b[0];

    const float* tbase = text + (size_t)b * NT * ND + 4 * lane;

    f32x4 acc[4];
    #pragma unroll
    for (int k = 0; k < 4; ++k) acc[k] = (f32x4){0.f, 0.f, 0.f, 0.f};
    float esum = 0.0f;

    unsigned mask = mkbits;
    while (mask) {                         // uniform loop, pair extraction
        const int r0 = __builtin_ctz(mask);
        mask &= mask - 1;
        if (mask) {
            // ---- dual-row body: 8 loads in flight, 2 shuffle chains ----
            const int r1 = __builtin_ctz(mask);
            mask &= mask - 1;
            const int i0 = wip[r0], i1 = wip[r1];     // L1-hit metadata
            const float* s0 = tbase + (size_t)(i0 > 0 ? i0 : 0) * ND;
            const float* s1 = tbase + (size_t)(i1 > 0 ? i1 : 0) * ND;
            f32x4 f0[4], f1[4];
            #pragma unroll
            for (int k = 0; k < 4; ++k) {
                f0[k] = *reinterpret_cast<const f32x4*>(s0 + 256 * k);
                f1[k] = *reinterpret_cast<const f32x4*>(s1 + 256 * k);
            }
            float d0 = 0.0f, d1 = 0.0f;
            #pragma unroll
            for (int k = 0; k < 4; ++k) {
                d0 += f0[k].x * wfrag[k].x + f0[k].y * wfrag[k].y
                    + f0[k].z * wfrag[k].z + f0[k].w * wfrag[k].w;
                d1 += f1[k].x * wfrag[k].x + f1[k].y * wfrag[k].y
                    + f1[k].z * wfrag[k].z + f1[k].w * wfrag[k].w;
            }
            #pragma unroll
            for (int sh = 1; sh < 64; sh <<= 1) {
                d0 += __shfl_xor(d0, sh);
                d1 += __shfl_xor(d1, sh);
            }
            const float e0 = __expf(d0 + bias);
            const float e1 = __expf(d1 + bias);
            esum += e0 + e1;
            #pragma unroll
            for (int k = 0; k < 4; ++k) {
                acc[k].x += e0 * f0[k].x + e1 * f1[k].x;
                acc[k].y += e0 * f0[k].y + e1 * f1[k].y;
                acc[k].z += e0 * f0[k].z + e1 * f1[k].z;
                acc[k].w += e0 * f0[k].w + e1 * f1[k].w;
            }
        } else {
            // ---- single-row tail ----
            const int i0 = wip[r0];
            const float* s0 = tbase + (size_t)(i0 > 0 ? i0 : 0) * ND;
            f32x4 f0[4];
            #pragma unroll
            for (int k = 0; k < 4; ++k)
                f0[k] = *reinterpret_cast<const f32x4*>(s0 + 256 * k);
            float d0 = 0.0f;
            #pragma unroll
            for (int k = 0; k < 4; ++k)
                d0 += f0[k].x * wfrag[k].x + f0[k].y * wfrag[k].y
                    + f0[k].z * wfrag[k].z + f0[k].w * wfrag[k].w;
            #pragma unroll
            for (int sh = 1; sh < 64; sh <<= 1)
                d0 += __shfl_xor(d0, sh);
            const float e0 = __expf(d0 + bias);
            esum += e0;
            #pragma unroll
            for (int k = 0; k < 4; ++k) {
                acc[k].x += e0 * f0[k].x;
                acc[k].y += e0 * f0[k].y;
                acc[k].z += e0 * f0[k].z;
                acc[k].w += e0 * f0[k].w;
            }
        }
    }

    const float inv = esum > 0.0f ? 1.0f / esum : 0.0f;
    #pragma unroll
    for (int k = 0; k < 4; ++k) {
        f32x4 o = acc[k];
        o.x *= inv; o.y *= inv; o.z *= inv; o.w *= inv;
        __builtin_nontemporal_store(o, reinterpret_cast<f32x4*>(orow + 256 * k));
    }
}

extern "C" void kernel_launch(void* const* d_in, const int* in_sizes, int n_in,
                              void* d_out, int out_size, void* d_ws, size_t ws_size,
                              hipStream_t stream) {
    const float* text  = (const float*)d_in[0];
    // d_in[1] = contextualized_embedding: unused by the reference.
    const int*   wi    = (const int*)d_in[2];
    const int*   wm    = (const int*)d_in[3];
    const int*   wim   = (const int*)d_in[4];
    const float* att_w = (const float*)d_in[5];
    const float* att_b = (const float*)d_in[6];
    float*       out   = (float*)d_out;

    span_attn_kernel<<<dim3(NB * NS), dim3(64), 0, stream>>>(
        text, wi, wm, wim, att_w, att_b, out);
}

// Round 12
// 15.469 us; speedup vs baseline: 3.2841x; 1.0101x over previous
//
#include <hip/hip_runtime.h>

#define NB 8
#define NT 2048
#define ND 1024
#define NS 512
#define NW 16

typedef float f32x4 __attribute__((ext_vector_type(4)));

// One WAVE (64-thread block) per span; grid 4096 -> HW refills CU slots as
// blocks finish (dynamic balancing). Lane l covers float cols 4l + 256k.
// QUAD-row main loop: 4 unmasked rows at once -> 16 x 16B loads in flight
// and 4 interleaved butterfly chains, halving latency-gated iterations vs
// the pair version (round 11: 15.6us, still latency-bound).
// Unnormalized-exp softmax; esum==0 -> zeros (matches reference all-masked).
// XCD swizzle: b = blockIdx & 7 keeps each XCD's gathers inside text[b].
__global__ __launch_bounds__(64) void span_attn_kernel(
    const float* __restrict__ text,   // [B, T, D]
    const int*   __restrict__ wi,     // [B, S, W]
    const int*   __restrict__ wm,     // [B, S, W]
    const int*   __restrict__ wim,    // [B, S]
    const float* __restrict__ att_w,  // [D]
    const float* __restrict__ att_b,  // [1]
    float*       __restrict__ out)    // [B, S, D]
{
    const int b    = blockIdx.x & (NB - 1);
    const int s    = blockIdx.x >> 3;
    const int bs   = b * NS + s;
    const int lane = threadIdx.x;

    float* orow = out + (size_t)bs * ND + 4 * lane;

    if (wim[bs] == 0) {                    // uniform: span is exactly 0
        #pragma unroll
        for (int k = 0; k < 4; ++k)
            __builtin_nontemporal_store((f32x4){0.f, 0.f, 0.f, 0.f},
                reinterpret_cast<f32x4*>(orow + 256 * k));
        return;
    }

    const int* wip = wi + (size_t)bs * NW;
    const int* wmp = wm + (size_t)bs * NW;

    unsigned mkbits = 0;
    #pragma unroll
    for (int q = 0; q < 4; ++q) {
        const int4 mv = *reinterpret_cast<const int4*>(wmp + 4 * q);
        mkbits |= (mv.x != 0 ? 1u : 0u) << (4 * q + 0);
        mkbits |= (mv.y != 0 ? 1u : 0u) << (4 * q + 1);
        mkbits |= (mv.z != 0 ? 1u : 0u) << (4 * q + 2);
        mkbits |= (mv.w != 0 ? 1u : 0u) << (4 * q + 3);
    }

    f32x4 wfrag[4];
    #pragma unroll
    for (int k = 0; k < 4; ++k)
        wfrag[k] = *reinterpret_cast<const f32x4*>(att_w + 4 * lane + 256 * k);
    const float bias = att_b[0];

    const float* tbase = text + (size_t)b * NT * ND + 4 * lane;

    f32x4 acc[4];
    #pragma unroll
    for (int k = 0; k < 4; ++k) acc[k] = (f32x4){0.f, 0.f, 0.f, 0.f};
    float esum = 0.0f;

    unsigned mask = mkbits;

    // ---- quad main loop: 16 loads in flight, 4 shuffle chains ----
    while (__popc(mask) >= 4) {
        const int r0 = __builtin_ctz(mask); mask &= mask - 1;
        const int r1 = __builtin_ctz(mask); mask &= mask - 1;
        const int r2 = __builtin_ctz(mask); mask &= mask - 1;
        const int r3 = __builtin_ctz(mask); mask &= mask - 1;
        const int i0 = wip[r0], i1 = wip[r1], i2 = wip[r2], i3 = wip[r3];
        const float* s0 = tbase + (size_t)(i0 > 0 ? i0 : 0) * ND;
        const float* s1 = tbase + (size_t)(i1 > 0 ? i1 : 0) * ND;
        const float* s2 = tbase + (size_t)(i2 > 0 ? i2 : 0) * ND;
        const float* s3 = tbase + (size_t)(i3 > 0 ? i3 : 0) * ND;
        f32x4 f0[4], f1[4], f2[4], f3[4];
        #pragma unroll
        for (int k = 0; k < 4; ++k) {
            f0[k] = *reinterpret_cast<const f32x4*>(s0 + 256 * k);
            f1[k] = *reinterpret_cast<const f32x4*>(s1 + 256 * k);
            f2[k] = *reinterpret_cast<const f32x4*>(s2 + 256 * k);
            f3[k] = *reinterpret_cast<const f32x4*>(s3 + 256 * k);
        }
        float d0 = 0.f, d1 = 0.f, d2 = 0.f, d3 = 0.f;
        #pragma unroll
        for (int k = 0; k < 4; ++k) {
            d0 += f0[k].x * wfrag[k].x + f0[k].y * wfrag[k].y
                + f0[k].z * wfrag[k].z + f0[k].w * wfrag[k].w;
            d1 += f1[k].x * wfrag[k].x + f1[k].y * wfrag[k].y
                + f1[k].z * wfrag[k].z + f1[k].w * wfrag[k].w;
            d2 += f2[k].x * wfrag[k].x + f2[k].y * wfrag[k].y
                + f2[k].z * wfrag[k].z + f2[k].w * wfrag[k].w;
            d3 += f3[k].x * wfrag[k].x + f3[k].y * wfrag[k].y
                + f3[k].z * wfrag[k].z + f3[k].w * wfrag[k].w;
        }
        #pragma unroll
        for (int sh = 1; sh < 64; sh <<= 1) {
            d0 += __shfl_xor(d0, sh);
            d1 += __shfl_xor(d1, sh);
            d2 += __shfl_xor(d2, sh);
            d3 += __shfl_xor(d3, sh);
        }
        const float e0 = __expf(d0 + bias);
        const float e1 = __expf(d1 + bias);
        const float e2 = __expf(d2 + bias);
        const float e3 = __expf(d3 + bias);
        esum += (e0 + e1) + (e2 + e3);
        #pragma unroll
        for (int k = 0; k < 4; ++k) {
            acc[k].x += e0 * f0[k].x + e1 * f1[k].x + e2 * f2[k].x + e3 * f3[k].x;
            acc[k].y += e0 * f0[k].y + e1 * f1[k].y + e2 * f2[k].y + e3 * f3[k].y;
            acc[k].z += e0 * f0[k].z + e1 * f1[k].z + e2 * f2[k].z + e3 * f3[k].z;
            acc[k].w += e0 * f0[k].w + e1 * f1[k].w + e2 * f2[k].w + e3 * f3[k].w;
        }
    }

    // ---- pair tail ----
    if (__popc(mask) >= 2) {
        const int r0 = __builtin_ctz(mask); mask &= mask - 1;
        const int r1 = __builtin_ctz(mask); mask &= mask - 1;
        const int i0 = wip[r0], i1 = wip[r1];
        const float* s0 = tbase + (size_t)(i0 > 0 ? i0 : 0) * ND;
        const float* s1 = tbase + (size_t)(i1 > 0 ? i1 : 0) * ND;
        f32x4 f0[4], f1[4];
        #pragma unroll
        for (int k = 0; k < 4; ++k) {
            f0[k] = *reinterpret_cast<const f32x4*>(s0 + 256 * k);
            f1[k] = *reinterpret_cast<const f32x4*>(s1 + 256 * k);
        }
        float d0 = 0.f, d1 = 0.f;
        #pragma unroll
        for (int k = 0; k < 4; ++k) {
            d0 += f0[k].x * wfrag[k].x + f0[k].y * wfrag[k].y
                + f0[k].z * wfrag[k].z + f0[k].w * wfrag[k].w;
            d1 += f1[k].x * wfrag[k].x + f1[k].y * wfrag[k].y
                + f1[k].z * wfrag[k].z + f1[k].w * wfrag[k].w;
        }
        #pragma unroll
        for (int sh = 1; sh < 64; sh <<= 1) {
            d0 += __shfl_xor(d0, sh);
            d1 += __shfl_xor(d1, sh);
        }
        const float e0 = __expf(d0 + bias);
        const float e1 = __expf(d1 + bias);
        esum += e0 + e1;
        #pragma unroll
        for (int k = 0; k < 4; ++k) {
            acc[k].x += e0 * f0[k].x + e1 * f1[k].x;
            acc[k].y += e0 * f0[k].y + e1 * f1[k].y;
            acc[k].z += e0 * f0[k].z + e1 * f1[k].z;
            acc[k].w += e0 * f0[k].w + e1 * f1[k].w;
        }
    }

    // ---- single tail ----
    if (mask) {
        const int r0 = __builtin_ctz(mask);
        const int i0 = wip[r0];
        const float* s0 = tbase + (size_t)(i0 > 0 ? i0 : 0) * ND;
        f32x4 f0[4];
        #pragma unroll
        for (int k = 0; k < 4; ++k)
            f0[k] = *reinterpret_cast<const f32x4*>(s0 + 256 * k);
        float d0 = 0.f;
        #pragma unroll
        for (int k = 0; k < 4; ++k)
            d0 += f0[k].x * wfrag[k].x + f0[k].y * wfrag[k].y
                + f0[k].z * wfrag[k].z + f0[k].w * wfrag[k].w;
        #pragma unroll
        for (int sh = 1; sh < 64; sh <<= 1)
            d0 += __shfl_xor(d0, sh);
        const float e0 = __expf(d0 + bias);
        esum += e0;
        #pragma unroll
        for (int k = 0; k < 4; ++k) {
            acc[k].x += e0 * f0[k].x;
            acc[k].y += e0 * f0[k].y;
            acc[k].z += e0 * f0[k].z;
            acc[k].w += e0 * f0[k].w;
        }
    }

    const float inv = esum > 0.0f ? 1.0f / esum : 0.0f;
    #pragma unroll
    for (int k = 0; k < 4; ++k) {
        f32x4 o = acc[k];
        o.x *= inv; o.y *= inv; o.z *= inv; o.w *= inv;
        __builtin_nontemporal_store(o, reinterpret_cast<f32x4*>(orow + 256 * k));
    }
}

extern "C" void kernel_launch(void* const* d_in, const int* in_sizes, int n_in,
                              void* d_out, int out_size, void* d_ws, size_t ws_size,
                              hipStream_t stream) {
    const float* text  = (const float*)d_in[0];
    // d_in[1] = contextualized_embedding: unused by the reference.
    const int*   wi    = (const int*)d_in[2];
    const int*   wm    = (const int*)d_in[3];
    const int*   wim   = (const int*)d_in[4];
    const float* att_w = (const float*)d_in[5];
    const float* att_b = (const float*)d_in[6];
    float*       out   = (float*)d_out;

    span_attn_kernel<<<dim3(NB * NS), dim3(64), 0, stream>>>(
        text, wi, wm, wim, att_w, att_b, out);
}